// Round 7
// baseline (422.157 us; speedup 1.0000x reference)
//
#include <hip/hip_runtime.h>

// FireLSTM: x[8192,512,4] fp32 -> LSTM(H=64) -> FC(64->1), out[8192] fp32.
//
// 256 blocks x 512 thr (8 waves) = 1 block/CU, 2 waves/SIMD. Block owns 32
// batches as TWO INDEPENDENT groups of 16. Waves 0-3 = G0, waves 4-7 = G1
// (round-robin wave->SIMD puts one G0 + one G1 wave per SIMD). Each group is
// R4's structure (4 waves split the gate dim; 12 mfma_f32_16x16x32_f16/step),
// but the groups run HALF A STEP apart with 2 barriers/step:
//   seg1: G0 MFMA_t            || G1 TRANS_{t-1}
//   seg2: G0 TRANS_t           || G1 MFMA_t
// -> on every SIMD, one wave is always in its trans phase: the trans pipe
// (the hard floor) is continuously fed instead of phase-locked idle (R4's
// 32% idle). Groups are data-independent; barriers are pure rendezvous.
// Parity audit: MFMA_t reads h at parity t&1; TRANS_t writes parity (t+1)&1;
// every produce->consume and WAR pair crosses >=1 barrier (checked per group).
//
// Cell update uses 7 trans (was 8): 4 exp2 (gates) + 1 exp2 (tanh(c)) +
// 2 rcp, by merging f*c + i*g over a common denominator:
//   c' = [c*(1+ei)(1+eg) + (1-eg)(1+ef)] / [(1+ef)(1+ei)(1+eg)]
//   h  = (1-et) / ((1+eo)(1+et)),  et = exp2(-clamp(2*log2e*c', +-60))
// Weights pre-scaled by log2e (2*log2e for g-gate). Bias enters the MFMA via
// K-slots 68/69 (A=1.0, B=bias hi+lo fp16) with persistent zero-C operand.
// h double-buffered fp16 XOR-swizzled LDS; x staged per 32 steps as fp16x4.

typedef float f32x4 __attribute__((ext_vector_type(4)));
typedef _Float16 f16x8 __attribute__((ext_vector_type(8)));
typedef _Float16 f16x4 __attribute__((ext_vector_type(4)));

#define TSEQ 512
#define IDIM 4
#define BPB 32              // 2 groups x 16 batches
#define TCH 32              // x staging chunk, in steps
#define L2E 1.44269504088896340736f

#if __has_builtin(__builtin_amdgcn_exp2f)
#define EX2(v) __builtin_amdgcn_exp2f(v)
#else
#define EX2(v) exp2f(v)
#endif
#define RCP(v) __builtin_amdgcn_rcpf(v)

__global__ __launch_bounds__(512, 2) void lstm_fused(
    const float* __restrict__ x,
    const float* __restrict__ W_ih,
    const float* __restrict__ W_hh,
    const float* __restrict__ b_ih,
    const float* __restrict__ b_hh,
    const float* __restrict__ W_fc,
    const float* __restrict__ b_fc,
    float* __restrict__ out)
{
    __shared__ __align__(16) _Float16 hbuf[2][2][16 * 64];  // [parity][group], 8 KB
    __shared__ __align__(8)  f16x4    xstage[2][16][33];    // [group][row][step]

    const int tid  = threadIdx.x;
    const int lane = tid & 63;
    const int wv   = tid >> 6;       // 0..7
    const int grp  = wv >> 2;        // 0 = G0, 1 = G1
    const int wvl  = wv & 3;         // h-column group within the 4-wave team
    const int b0   = blockIdx.x * BPB;
    const int r    = lane & 15;      // D col (h within group) / A row (batch)
    const int g16  = lane >> 4;      // k-group

    // ---- B-fragments: 4 gate types x K=96, pre-scaled by log2e, registers ----
    // k = ks*32 + 8*g16 + j. ks=2 frag: k=64..67 -> W_ih, k=68,69 -> bias
    // (hi,lo fp16) against A=1.0, k>=70 -> 0.
    f16x8 bfrag[4][3];
    #pragma unroll
    for (int t4 = 0; t4 < 4; ++t4) {
        const float sc = (t4 == 2) ? 2.0f * L2E : L2E;   // g-gate gets tanh's 2x
        const int g = t4 * 64 + wvl * 16 + r;
        #pragma unroll
        for (int ks = 0; ks < 2; ++ks) {                 // k 0..63: W_hh
            const float* p = W_hh + g * 64 + ks * 32 + g16 * 8;
            f16x8 f;
            #pragma unroll
            for (int j = 0; j < 8; ++j) f[j] = (_Float16)(p[j] * sc);
            bfrag[t4][ks] = f;
        }
        f16x8 f;
        #pragma unroll
        for (int j = 0; j < 8; ++j) f[j] = (_Float16)0.0f;
        if (g16 == 0) {
            #pragma unroll
            for (int j = 0; j < 4; ++j) f[j] = (_Float16)(W_ih[g * IDIM + j] * sc);
            float biasf = (b_ih[g] + b_hh[g]) * sc;
            _Float16 hi = (_Float16)biasf;
            f[4] = hi;
            f[5] = (_Float16)(biasf - (float)hi);
        }
        bfrag[t4][2] = f;
    }
    const float wfc = W_fc[lane];
    const float bfc = b_fc[0];
    const f32x4 zero4 = {0.f, 0.f, 0.f, 0.f};            // persistent C operand

    float c_reg[4] = {0.f, 0.f, 0.f, 0.f};
    // zero parity-0 for both groups (h_{-1} = 0)
    for (int i = tid; i < 2 * 16 * 64; i += 512)
        ((_Float16*)&hbuf[0][0][0])[i] = (_Float16)0.0f;

    // ---- x chunk-0 prefetch: 32 rows x 32 steps, 2 float4/thread ----
    const int xrow = tid >> 4;           // 0..31 block-local batch row
    const int xgp  = xrow >> 4, xlr = xrow & 15;
    const int xtf  = tid & 15;           // steps 2*xtf, 2*xtf+1 of the chunk
    const float* xg = x + ((size_t)(b0 + xrow) * TSEQ + 2 * xtf) * IDIM;
    float4 xn0 = *(const float4*)xg;
    float4 xn1 = *(const float4*)(xg + IDIM);

    // ---- precomputed LDS byte offsets ----
    const int hbase = r * 128;
    const int hs0 = ((g16 + 0) << 4) ^ ((r & 7) << 4);
    const int hs1 = ((g16 + 4) << 4) ^ ((r & 7) << 4);
    int hw[4];
    #pragma unroll
    for (int q = 0; q < 4; ++q) {
        const int bat = 4 * g16 + q;                     // D row = local batch
        hw[q] = (bat * 128 + (wvl * 16 + r) * 2) ^ ((bat & 7) << 4);
    }
    char* hbB = (char*)&hbuf[0][0][0];
    const int gofs = grp * 2048;                         // group offset in a parity
    const f16x4* xsb = &xstage[grp][r][0];

    auto STAGE = [&]() {
        f16x4 s0, s1;
        s0[0] = (_Float16)xn0.x; s0[1] = (_Float16)xn0.y;
        s0[2] = (_Float16)xn0.z; s0[3] = (_Float16)xn0.w;
        s1[0] = (_Float16)xn1.x; s1[1] = (_Float16)xn1.y;
        s1[2] = (_Float16)xn1.z; s1[3] = (_Float16)xn1.w;
        xstage[xgp][xlr][2 * xtf]     = s0;
        xstage[xgp][xlr][2 * xtf + 1] = s1;
    };

    auto MFMA = [&](int parity, int tt, f32x4* acc) {
        const char* rb = hbB + parity * 4096 + gofs;
        f16x8 a0 = *(const f16x8*)(rb + hbase + hs0);
        f16x8 a1 = *(const f16x8*)(rb + hbase + hs1);
        f16x4 xv = xsb[tt];
        f16x8 ax;
        ax[0] = xv[0]; ax[1] = xv[1]; ax[2] = xv[2]; ax[3] = xv[3];
        ax[4] = (_Float16)1.0f; ax[5] = (_Float16)1.0f;   // bias slots (k=68,69)
        ax[6] = (_Float16)0.0f; ax[7] = (_Float16)0.0f;
        __builtin_amdgcn_s_setprio(1);
        #pragma unroll
        for (int t4 = 0; t4 < 4; ++t4) {
            f32x4 a;
            a = __builtin_amdgcn_mfma_f32_16x16x32_f16(a0, bfrag[t4][0], zero4, 0, 0, 0);
            a = __builtin_amdgcn_mfma_f32_16x16x32_f16(a1, bfrag[t4][1], a, 0, 0, 0);
            a = __builtin_amdgcn_mfma_f32_16x16x32_f16(ax, bfrag[t4][2], a, 0, 0, 0);
            acc[t4] = a;
        }
        __builtin_amdgcn_s_setprio(0);
    };

    auto TRANS = [&](int parityW, const f32x4* acc) {
        char* wb = hbB + parityW * 4096 + gofs;
        #pragma unroll
        for (int q = 0; q < 4; ++q) {
            float ei = EX2(-acc[0][q]);                  // e^-ai
            float ef = EX2(-acc[1][q]);
            float eg = EX2(-acc[2][q]);                  // e^-2ag
            float eo = EX2(-acc[3][q]);
            float A  = 1.f + ei, F = 1.f + ef;
            float Gp = 1.f + eg, Gm = 1.f - eg;
            float P   = A * Gp;
            float num = c_reg[q] * P + Gm * F;           // c*P + (1-eg)*F
            float c   = num * RCP(P * F);                // merged: 1 rcp for f*c+i*g
            c_reg[q] = c;
            float uc = fminf(fmaxf(c * (2.0f * L2E), -60.f), 60.f);
            float et = EX2(-uc);                         // e^-2c
            float h  = (1.f - et) * RCP((1.f + eo) * (1.f + et));  // o*tanh(c)
            *(_Float16*)(wb + hw[q]) = (_Float16)h;
        }
    };

    // ---- prologue: stage chunk 0, peel t=0 ----
    STAGE();
    __syncthreads();
    xn0 = *(const float4*)(xg + TCH * IDIM);
    xn1 = *(const float4*)(xg + TCH * IDIM + IDIM);

    f32x4 acc[4];
    if (grp == 0) MFMA(0, 0, acc);        // G0: MFMA_0 (reads zeroed parity 0)
    __syncthreads();
    if (grp == 0) TRANS(1, acc);          // G0: TRANS_0 -> parity 1
    else          MFMA(0, 0, acc);        // G1: MFMA_0
    __syncthreads();

    // ---- main loop: t = 1..511, two rendezvous barriers per step ----
    for (int t = 1; t < TSEQ; ++t) {
        if ((t & (TCH - 1)) == 0) {
            STAGE();                       // prev seg2 barrier ordered last reads
            __syncthreads();
            if (t + TCH < TSEQ) {
                xn0 = *(const float4*)(xg + (size_t)(t + TCH) * IDIM);
                xn1 = *(const float4*)(xg + (size_t)(t + TCH) * IDIM + IDIM);
            }
        }
        const int tt = t & (TCH - 1);
        const int p  = t & 1;
        if (grp == 0) MFMA(p, tt, acc);    // G0: MFMA_t   (reads parity t&1)
        else          TRANS(p, acc);       // G1: TRANS_{t-1} (writes parity t&1)
        __syncthreads();
        if (grp == 0) TRANS(p ^ 1, acc);   // G0: TRANS_t  (writes parity (t+1)&1)
        else          MFMA(p, tt, acc);    // G1: MFMA_t   (reads parity t&1)
        __syncthreads();
    }
    // epilogue: G1 still owes TRANS_511 -> parity (512)&1 = 0
    if (grp == 1) TRANS(0, acc);
    __syncthreads();

    // ---- FC: out[b] = sum_h h[b][h]*W_fc[h] + b_fc ; final h in parity 0 ----
    #pragma unroll
    for (int q = 0; q < 4; ++q) {
        const int bat  = wvl * 4 + q;
        const int byte = (bat * 128 + lane * 2) ^ ((bat & 7) << 4);
        float hv = (float)*(const _Float16*)(hbB + gofs + byte);
        float partial = hv * wfc;
        #pragma unroll
        for (int off = 32; off > 0; off >>= 1)
            partial += __shfl_down(partial, off);
        if (lane == 0) out[b0 + grp * 16 + bat] = partial + bfc;
    }
}

extern "C" void kernel_launch(void* const* d_in, const int* in_sizes, int n_in,
                              void* d_out, int out_size, void* d_ws, size_t ws_size,
                              hipStream_t stream) {
    const float* x    = (const float*)d_in[0];
    const float* W_ih = (const float*)d_in[1];
    const float* W_hh = (const float*)d_in[2];
    const float* b_ih = (const float*)d_in[3];
    const float* b_hh = (const float*)d_in[4];
    const float* W_fc = (const float*)d_in[5];
    const float* b_fc = (const float*)d_in[6];
    float* out = (float*)d_out;

    const int B = in_sizes[0] / (TSEQ * IDIM);   // 8192
    lstm_fused<<<B / BPB, 512, 0, stream>>>(x, W_ih, W_hh, b_ih, b_hh, W_fc, b_fc, out);
}

// Round 8
// 338.667 us; speedup vs baseline: 1.2465x; 1.2465x over previous
//
#include <hip/hip_runtime.h>

// FireLSTM: x[8192,512,4] fp32 -> LSTM(H=64) -> FC(64->1), out[8192] fp32.
//
// R4 geometry (the forced one): 512 blocks x 256 thr (4 waves) = 2 blocks/CU,
// 2 waves/SIMD. Block owns 16 batches; wave wv owns h-cols [16wv,16wv+16) for
// all 4 gate types. Per step: 12x mfma_f32_16x16x32_f16, activations fully
// register-local (D cell (batch=4*g16+q, h=16wv+r) holds all 4 gate types),
// h double-buffered fp16 XOR-swizzled LDS, ONE barrier/step.
//
// R8 deltas (all in-place):
//  1. x-MFMA hoist: the ax*W_x+bias MFMA (4 of 12) depends only on x_{t+1},
//     not h_t -> computed BEFORE the barrier into accX; post-barrier chain is
//     2 dependent MFMAs per tile seeded with C=accX.
//  2. 7-trans cell update (merged rcp, R7-verified):
//     c' = [c*(1+ei)(1+eg) + (1-eg)(1+ef)] * rcp((1+ei)(1+eg)(1+ef))
//  3. Raw step barrier {lgkmcnt(0); s_barrier; sched_barrier(0)} -- no vmcnt
//     drain -> x global prefetch floats freely. xstage double-buffered; chunk
//     c+1 staged mid-chunk c (loads issued one chunk earlier). No chunk barrier.
// Bias enters via K-slots 68/69 (A=1.0, B=bias hi+lo fp16); zero-C operand;
// weights pre-scaled by log2e (2*log2e for g-gate).

typedef float f32x4 __attribute__((ext_vector_type(4)));
typedef _Float16 f16x8 __attribute__((ext_vector_type(8)));
typedef _Float16 f16x4 __attribute__((ext_vector_type(4)));

#define TSEQ 512
#define IDIM 4
#define BPB 16
#define TCH 32
#define NCH (TSEQ / TCH)
#define L2E 1.44269504088896340736f

#if __has_builtin(__builtin_amdgcn_exp2f)
#define EX2(v) __builtin_amdgcn_exp2f(v)
#else
#define EX2(v) exp2f(v)
#endif
#define RCP(v) __builtin_amdgcn_rcpf(v)

// lgkmcnt(0) flushes our ds_writes; s_barrier rendezvous; sched_barrier(0)
// stops post-barrier ds_reads hoisting above (rule #18). No vmcnt drain.
#define STEP_BARRIER() do {                                   \
    asm volatile("s_waitcnt lgkmcnt(0)" ::: "memory");        \
    __builtin_amdgcn_s_barrier();                             \
    __builtin_amdgcn_sched_barrier(0);                        \
} while (0)

__global__ __launch_bounds__(256, 2) void lstm_fused(
    const float* __restrict__ x,
    const float* __restrict__ W_ih,
    const float* __restrict__ W_hh,
    const float* __restrict__ b_ih,
    const float* __restrict__ b_hh,
    const float* __restrict__ W_fc,
    const float* __restrict__ b_fc,
    float* __restrict__ out)
{
    __shared__ __align__(16) _Float16 hbuf[2][BPB * 64];   // 4 KB, XOR-swizzled
    __shared__ __align__(16) f16x4    xstage[2][BPB][33];  // 2 x 4224 B

    const int tid  = threadIdx.x;
    const int lane = tid & 63;
    const int wv   = tid >> 6;
    const int b0   = blockIdx.x * BPB;
    const int r    = lane & 15;
    const int g16  = lane >> 4;

    // ---- B-fragments: 4 types x K=96, pre-scaled. k = ks*32 + 8*g16 + j.
    // ks=2: k=64..67 -> W_ih, k=68,69 -> bias hi/lo (vs A=1.0), k>=70 -> 0.
    f16x8 bfrag[4][3];
    #pragma unroll
    for (int t4 = 0; t4 < 4; ++t4) {
        const float sc = (t4 == 2) ? 2.0f * L2E : L2E;
        const int g = t4 * 64 + wv * 16 + r;
        #pragma unroll
        for (int ks = 0; ks < 2; ++ks) {
            const float* p = W_hh + g * 64 + ks * 32 + g16 * 8;
            f16x8 f;
            #pragma unroll
            for (int j = 0; j < 8; ++j) f[j] = (_Float16)(p[j] * sc);
            bfrag[t4][ks] = f;
        }
        f16x8 f;
        #pragma unroll
        for (int j = 0; j < 8; ++j) f[j] = (_Float16)0.0f;
        if (g16 == 0) {
            #pragma unroll
            for (int j = 0; j < 4; ++j) f[j] = (_Float16)(W_ih[g * IDIM + j] * sc);
            float biasf = (b_ih[g] + b_hh[g]) * sc;
            _Float16 hi = (_Float16)biasf;
            f[4] = hi;
            f[5] = (_Float16)(biasf - (float)hi);
        }
        bfrag[t4][2] = f;
    }
    const float wfc = W_fc[lane];
    const float bfc = b_fc[0];
    const f32x4 zero4 = {0.f, 0.f, 0.f, 0.f};

    float c_reg[4] = {0.f, 0.f, 0.f, 0.f};
    for (int i = tid; i < BPB * 64; i += 256) hbuf[0][i] = (_Float16)0.0f;

    // ---- x: thread loads rows bb0, bb0+8 at chunk-step tf (2 float4) ----
    const int bb0 = tid >> 5, tf = tid & 31;
    const float* xg0 = x + ((size_t)(b0 + bb0)     * TSEQ + tf) * IDIM;
    const float* xg1 = x + ((size_t)(b0 + bb0 + 8) * TSEQ + tf) * IDIM;
    float4 xn0 = *(const float4*)xg0;
    float4 xn1 = *(const float4*)xg1;
    // stage chunk 0 into xbuf 0
    {
        f16x4 s0, s1;
        s0[0] = (_Float16)xn0.x; s0[1] = (_Float16)xn0.y;
        s0[2] = (_Float16)xn0.z; s0[3] = (_Float16)xn0.w;
        s1[0] = (_Float16)xn1.x; s1[1] = (_Float16)xn1.y;
        s1[2] = (_Float16)xn1.z; s1[3] = (_Float16)xn1.w;
        xstage[0][bb0][tf]     = s0;
        xstage[0][bb0 + 8][tf] = s1;
    }
    __syncthreads();                       // once; chunk-1 loads issued after
    xn0 = *(const float4*)(xg0 + TCH * IDIM);
    xn1 = *(const float4*)(xg1 + TCH * IDIM);

    // ---- precomputed LDS byte offsets ----
    const int hbase = r * 128;
    const int hs0 = ((g16 + 0) << 4) ^ ((r & 7) << 4);
    const int hs1 = ((g16 + 4) << 4) ^ ((r & 7) << 4);
    int hw[4];
    #pragma unroll
    for (int q = 0; q < 4; ++q) {
        const int bat = 4 * g16 + q;
        hw[q] = (bat * 128 + (wv * 16 + r) * 2) ^ ((bat & 7) << 4);
    }
    char* hbB = (char*)&hbuf[0][0];
    const char* xsB = (const char*)&xstage[0][0][0];
    const int xrow = r * 33 * 8;           // row-r byte offset within one xbuf

    // persistent ax: slots 4,5 = 1.0 (bias), 6,7 = 0
    f16x8 axr;
    axr[4] = (_Float16)1.0f; axr[5] = (_Float16)1.0f;
    axr[6] = (_Float16)0.0f; axr[7] = (_Float16)0.0f;

    // accX for t=0 (x_0 from xbuf0 slot 0)
    f32x4 accX[4];
    {
        f16x4 xv = *(const f16x4*)(xsB + xrow);
        axr[0] = xv[0]; axr[1] = xv[1]; axr[2] = xv[2]; axr[3] = xv[3];
        #pragma unroll
        for (int t4 = 0; t4 < 4; ++t4)
            accX[t4] = __builtin_amdgcn_mfma_f32_16x16x32_f16(axr, bfrag[t4][2], zero4, 0, 0, 0);
    }

    // one sub-step; P = parity of t (compile-time)
    auto substep = [&](int t, int P) {
        const char* rb = hbB + P * 2048;         // h_{t-1}
        char*       wb = hbB + (P ^ 1) * 2048;   // h_t
        f16x8 a0 = *(const f16x8*)(rb + hbase + hs0);
        f16x8 a1 = *(const f16x8*)(rb + hbase + hs1);

        f32x4 acc2[4];
        __builtin_amdgcn_s_setprio(1);
        #pragma unroll
        for (int t4 = 0; t4 < 4; ++t4) {
            f32x4 a;
            a = __builtin_amdgcn_mfma_f32_16x16x32_f16(a0, bfrag[t4][0], accX[t4], 0, 0, 0);
            a = __builtin_amdgcn_mfma_f32_16x16x32_f16(a1, bfrag[t4][1], a, 0, 0, 0);
            acc2[t4] = a;
        }
        __builtin_amdgcn_s_setprio(0);

        // hoisted x-MFMA for step t+1 (independent of h_t; fills MFMA pipe
        // while this wave's TRANS waits on acc2 and partner wave computes)
        {
            const int tb = t + 1;
            f16x4 xv = *(const f16x4*)(xsB + ((tb >> 5) & 1) * 4224 + xrow + (tb & 31) * 8);
            axr[0] = xv[0]; axr[1] = xv[1]; axr[2] = xv[2]; axr[3] = xv[3];
            __builtin_amdgcn_s_setprio(1);
            #pragma unroll
            for (int t4 = 0; t4 < 4; ++t4)
                accX[t4] = __builtin_amdgcn_mfma_f32_16x16x32_f16(axr, bfrag[t4][2], zero4, 0, 0, 0);
            __builtin_amdgcn_s_setprio(0);
        }

        // 7-trans cell update (4 gate exp2 + merged-rcp c + tanh exp2 + rcp)
        #pragma unroll
        for (int q = 0; q < 4; ++q) {
            float ei = EX2(-acc2[0][q]);
            float ef = EX2(-acc2[1][q]);
            float eg = EX2(-acc2[2][q]);
            float eo = EX2(-acc2[3][q]);
            float A  = 1.f + ei, F = 1.f + ef;
            float Gp = 1.f + eg, Gm = 1.f - eg;
            float P2  = A * Gp;
            float num = c_reg[q] * P2 + Gm * F;
            float c   = num * RCP(P2 * F);
            c_reg[q] = c;
            float uc = fminf(fmaxf(c * (2.0f * L2E), -60.f), 60.f);
            float et = EX2(-uc);
            float h  = (1.f - et) * RCP((1.f + eo) * (1.f + et));
            *(_Float16*)(wb + hw[q]) = (_Float16)h;
        }
        STEP_BARRIER();
    };

    for (int t = 0; t < TSEQ; t += 2) {
        if ((t & (TCH - 1)) == 16) {
            const int c = t >> 5;                // current chunk
            if (c + 1 < NCH) {                   // stage chunk c+1 (regs arrived)
                f16x4 s0, s1;
                s0[0] = (_Float16)xn0.x; s0[1] = (_Float16)xn0.y;
                s0[2] = (_Float16)xn0.z; s0[3] = (_Float16)xn0.w;
                s1[0] = (_Float16)xn1.x; s1[1] = (_Float16)xn1.y;
                s1[2] = (_Float16)xn1.z; s1[3] = (_Float16)xn1.w;
                f16x4* dst = &xstage[(c + 1) & 1][0][0];
                dst[bb0 * 33 + tf]       = s0;
                dst[(bb0 + 8) * 33 + tf] = s1;
                if (c + 2 < NCH) {               // issue loads for chunk c+2
                    xn0 = *(const float4*)(xg0 + (size_t)(c + 2) * TCH * IDIM);
                    xn1 = *(const float4*)(xg1 + (size_t)(c + 2) * TCH * IDIM);
                }
            }
        }
        substep(t,     0);
        substep(t + 1, 1);
    }

    // ---- FC epilogue: final h in parity 0 (TRANS_511 wrote parity 0) ----
    #pragma unroll
    for (int q = 0; q < 4; ++q) {
        const int bat  = wv * 4 + q;
        const int byte = (bat * 128 + lane * 2) ^ ((bat & 7) << 4);
        float hv = (float)*(const _Float16*)(hbB + byte);
        float partial = hv * wfc;
        #pragma unroll
        for (int off = 32; off > 0; off >>= 1)
            partial += __shfl_down(partial, off);
        if (lane == 0) out[b0 + bat] = partial + bfc;
    }
}

extern "C" void kernel_launch(void* const* d_in, const int* in_sizes, int n_in,
                              void* d_out, int out_size, void* d_ws, size_t ws_size,
                              hipStream_t stream) {
    const float* x    = (const float*)d_in[0];
    const float* W_ih = (const float*)d_in[1];
    const float* W_hh = (const float*)d_in[2];
    const float* b_ih = (const float*)d_in[3];
    const float* b_hh = (const float*)d_in[4];
    const float* W_fc = (const float*)d_in[5];
    const float* b_fc = (const float*)d_in[6];
    float* out = (float*)d_out;

    const int B = in_sizes[0] / (TSEQ * IDIM);   // 8192
    lstm_fused<<<B / BPB, 256, 0, stream>>>(x, W_ih, W_hh, b_ih, b_hh, W_fc, b_fc, out);
}

// Round 9
// 323.933 us; speedup vs baseline: 1.3032x; 1.0455x over previous
//
#include <hip/hip_runtime.h>

// FireLSTM: x[8192,512,4] fp32 -> LSTM(H=64) -> FC(64->1), out[8192] fp32.
//
// R4 geometry (forced): 512 blocks x 256 thr (4 waves) = 2 blocks/CU, 2
// waves/SIMD (one wave of each co-resident block per SIMD). Block owns 16
// batches; wave wv owns h-cols [16wv,16wv+16) for all 4 gate types. Per step:
// 12x mfma_f32_16x16x32_f16 (4 tiles x K=96=[h|x+bias|pad], 3-chain), all 4
// gate types of a cell land in the same thread regs -> activation+state
// update fully register-local. h double-buffered fp16 XOR-swizzled LDS, ONE
// barrier/step.
//
// R9 deltas vs R8:
//  1. sched_barrier(0) REMOVED from the step barrier (m141: order-pinning
//     defeats the scheduler; asm("memory")+s_barrier already orders mem ops).
//  2. accX hoist reverted -> plain 3-MFMA chain (R8 showed the hoist was
//     neutral-negative); k-slot bias (68/69 vs A=1.0) + zero-C kept.
//  3. Anti-phase: co-resident block pairs phase-lock (both in TRANS at once
//     -> VALU contention; both in barrier at once -> dead SIMD). One block of
//     each pair sleeps ~832 cyc once at start; identical self-timed loops
//     preserve the offset, so wave A's TRANS fills wave B's MFMA/LDS window.
//  Kept from R8: 7-trans cell update (merged rcp), raw lgkm-only step barrier
//  (no vmcnt drain ever), double-buffered x chunk staging (loads in flight 32
//  steps, consumed via register dependency only).

typedef float f32x4 __attribute__((ext_vector_type(4)));
typedef _Float16 f16x8 __attribute__((ext_vector_type(8)));
typedef _Float16 f16x4 __attribute__((ext_vector_type(4)));

#define TSEQ 512
#define IDIM 4
#define BPB 16
#define TCH 32
#define NCH (TSEQ / TCH)
#define L2E 1.44269504088896340736f

#if __has_builtin(__builtin_amdgcn_exp2f)
#define EX2(v) __builtin_amdgcn_exp2f(v)
#else
#define EX2(v) exp2f(v)
#endif
#define RCP(v) __builtin_amdgcn_rcpf(v)

// lgkmcnt(0) makes our ds_writes visible; s_barrier rendezvous. No vmcnt
// drain (x prefetch floats free); no sched_barrier (let the compiler move
// register work across the boundary -- memory ops are ordered by the asm
// "memory" clobber + barrier already).
#define STEP_BARRIER() do {                                   \
    asm volatile("s_waitcnt lgkmcnt(0)" ::: "memory");        \
    __builtin_amdgcn_s_barrier();                             \
} while (0)

__global__ __launch_bounds__(256, 2) void lstm_fused(
    const float* __restrict__ x,
    const float* __restrict__ W_ih,
    const float* __restrict__ W_hh,
    const float* __restrict__ b_ih,
    const float* __restrict__ b_hh,
    const float* __restrict__ W_fc,
    const float* __restrict__ b_fc,
    float* __restrict__ out)
{
    __shared__ __align__(16) _Float16 hbuf[2][BPB * 64];   // 4 KB, XOR-swizzled
    __shared__ __align__(16) f16x4    xstage[2][BPB][33];  // 2 x 4224 B

    const int tid  = threadIdx.x;
    const int lane = tid & 63;
    const int wv   = tid >> 6;
    const int b0   = blockIdx.x * BPB;
    const int r    = lane & 15;
    const int g16  = lane >> 4;

    // ---- B-fragments: 4 types x K=96, pre-scaled. k = ks*32 + 8*g16 + j.
    // ks=2: k=64..67 -> W_ih, k=68,69 -> bias hi/lo (vs A=1.0), k>=70 -> 0.
    f16x8 bfrag[4][3];
    #pragma unroll
    for (int t4 = 0; t4 < 4; ++t4) {
        const float sc = (t4 == 2) ? 2.0f * L2E : L2E;
        const int g = t4 * 64 + wv * 16 + r;
        #pragma unroll
        for (int ks = 0; ks < 2; ++ks) {
            const float* p = W_hh + g * 64 + ks * 32 + g16 * 8;
            f16x8 f;
            #pragma unroll
            for (int j = 0; j < 8; ++j) f[j] = (_Float16)(p[j] * sc);
            bfrag[t4][ks] = f;
        }
        f16x8 f;
        #pragma unroll
        for (int j = 0; j < 8; ++j) f[j] = (_Float16)0.0f;
        if (g16 == 0) {
            #pragma unroll
            for (int j = 0; j < 4; ++j) f[j] = (_Float16)(W_ih[g * IDIM + j] * sc);
            float biasf = (b_ih[g] + b_hh[g]) * sc;
            _Float16 hi = (_Float16)biasf;
            f[4] = hi;
            f[5] = (_Float16)(biasf - (float)hi);
        }
        bfrag[t4][2] = f;
    }
    const float wfc = W_fc[lane];
    const float bfc = b_fc[0];
    const f32x4 zero4 = {0.f, 0.f, 0.f, 0.f};

    float c_reg[4] = {0.f, 0.f, 0.f, 0.f};
    for (int i = tid; i < BPB * 64; i += 256) hbuf[0][i] = (_Float16)0.0f;

    // ---- x: thread loads rows bb0, bb0+8 at chunk-step tf (2 float4) ----
    const int bb0 = tid >> 5, tf = tid & 31;
    const float* xg0 = x + ((size_t)(b0 + bb0)     * TSEQ + tf) * IDIM;
    const float* xg1 = x + ((size_t)(b0 + bb0 + 8) * TSEQ + tf) * IDIM;
    float4 xn0 = *(const float4*)xg0;
    float4 xn1 = *(const float4*)xg1;
    // stage chunk 0 into xbuf 0
    {
        f16x4 s0, s1;
        s0[0] = (_Float16)xn0.x; s0[1] = (_Float16)xn0.y;
        s0[2] = (_Float16)xn0.z; s0[3] = (_Float16)xn0.w;
        s1[0] = (_Float16)xn1.x; s1[1] = (_Float16)xn1.y;
        s1[2] = (_Float16)xn1.z; s1[3] = (_Float16)xn1.w;
        xstage[0][bb0][tf]     = s0;
        xstage[0][bb0 + 8][tf] = s1;
    }
    __syncthreads();                       // once; chunk-1 loads issued after
    xn0 = *(const float4*)(xg0 + TCH * IDIM);
    xn1 = *(const float4*)(xg1 + TCH * IDIM);

    // ---- anti-phase: one block of each co-resident pair sleeps ~832 cyc ----
    // (covers both plausible pairings: consecutive ids and id +/- 256)
    if (((blockIdx.x ^ (blockIdx.x >> 8)) & 1) != 0)
        __builtin_amdgcn_s_sleep(13);

    // ---- precomputed LDS byte offsets ----
    const int hbase = r * 128;
    const int hs0 = ((g16 + 0) << 4) ^ ((r & 7) << 4);
    const int hs1 = ((g16 + 4) << 4) ^ ((r & 7) << 4);
    int hw[4];
    #pragma unroll
    for (int q = 0; q < 4; ++q) {
        const int bat = 4 * g16 + q;
        hw[q] = (bat * 128 + (wv * 16 + r) * 2) ^ ((bat & 7) << 4);
    }
    char* hbB = (char*)&hbuf[0][0];
    const char* xsB = (const char*)&xstage[0][0][0];
    const int xrow = r * 33 * 8;           // row-r byte offset within one xbuf

    // one sub-step; P = parity of t (compile-time)
    auto substep = [&](int t, int P) {
        const char* rb = hbB + P * 2048;         // h_{t-1}
        char*       wb = hbB + (P ^ 1) * 2048;   // h_t
        f16x8 a0 = *(const f16x8*)(rb + hbase + hs0);
        f16x8 a1 = *(const f16x8*)(rb + hbase + hs1);
        f16x4 xv = *(const f16x4*)(xsB + ((t >> 5) & 1) * 4224 + xrow + (t & 31) * 8);
        f16x8 ax;
        ax[0] = xv[0]; ax[1] = xv[1]; ax[2] = xv[2]; ax[3] = xv[3];
        ax[4] = (_Float16)1.0f; ax[5] = (_Float16)1.0f;   // bias slots (k=68,69)
        ax[6] = (_Float16)0.0f; ax[7] = (_Float16)0.0f;

        f32x4 acc[4];
        __builtin_amdgcn_s_setprio(1);
        #pragma unroll
        for (int t4 = 0; t4 < 4; ++t4) {
            f32x4 a;
            a = __builtin_amdgcn_mfma_f32_16x16x32_f16(a0, bfrag[t4][0], zero4, 0, 0, 0);
            a = __builtin_amdgcn_mfma_f32_16x16x32_f16(a1, bfrag[t4][1], a, 0, 0, 0);
            a = __builtin_amdgcn_mfma_f32_16x16x32_f16(ax, bfrag[t4][2], a, 0, 0, 0);
            acc[t4] = a;
        }
        __builtin_amdgcn_s_setprio(0);

        // 7-trans cell update (4 gate exp2 + merged-rcp c + tanh exp2 + rcp)
        #pragma unroll
        for (int q = 0; q < 4; ++q) {
            float ei = EX2(-acc[0][q]);
            float ef = EX2(-acc[1][q]);
            float eg = EX2(-acc[2][q]);
            float eo = EX2(-acc[3][q]);
            float A  = 1.f + ei, F = 1.f + ef;
            float Gp = 1.f + eg, Gm = 1.f - eg;
            float P2  = A * Gp;
            float num = c_reg[q] * P2 + Gm * F;
            float c   = num * RCP(P2 * F);
            c_reg[q] = c;
            float uc = fminf(fmaxf(c * (2.0f * L2E), -60.f), 60.f);
            float et = EX2(-uc);
            float h  = (1.f - et) * RCP((1.f + eo) * (1.f + et));
            *(_Float16*)(wb + hw[q]) = (_Float16)h;
        }
        STEP_BARRIER();
    };

    for (int t = 0; t < TSEQ; t += 2) {
        if ((t & (TCH - 1)) == 16) {
            const int c = t >> 5;                // current chunk
            if (c + 1 < NCH) {                   // stage chunk c+1 (regs arrived)
                f16x4 s0, s1;
                s0[0] = (_Float16)xn0.x; s0[1] = (_Float16)xn0.y;
                s0[2] = (_Float16)xn0.z; s0[3] = (_Float16)xn0.w;
                s1[0] = (_Float16)xn1.x; s1[1] = (_Float16)xn1.y;
                s1[2] = (_Float16)xn1.z; s1[3] = (_Float16)xn1.w;
                f16x4* dst = &xstage[(c + 1) & 1][0][0];
                dst[bb0 * 33 + tf]       = s0;
                dst[(bb0 + 8) * 33 + tf] = s1;
                if (c + 2 < NCH) {               // issue loads for chunk c+2
                    xn0 = *(const float4*)(xg0 + (size_t)(c + 2) * TCH * IDIM);
                    xn1 = *(const float4*)(xg1 + (size_t)(c + 2) * TCH * IDIM);
                }
            }
        }
        substep(t,     0);
        substep(t + 1, 1);
    }

    // ---- FC epilogue: final h in parity 0 (TRANS_511 wrote parity 0) ----
    #pragma unroll
    for (int q = 0; q < 4; ++q) {
        const int bat  = wv * 4 + q;
        const int byte = (bat * 128 + lane * 2) ^ ((bat & 7) << 4);
        float hv = (float)*(const _Float16*)(hbB + byte);
        float partial = hv * wfc;
        #pragma unroll
        for (int off = 32; off > 0; off >>= 1)
            partial += __shfl_down(partial, off);
        if (lane == 0) out[b0 + bat] = partial + bfc;
    }
}

extern "C" void kernel_launch(void* const* d_in, const int* in_sizes, int n_in,
                              void* d_out, int out_size, void* d_ws, size_t ws_size,
                              hipStream_t stream) {
    const float* x    = (const float*)d_in[0];
    const float* W_ih = (const float*)d_in[1];
    const float* W_hh = (const float*)d_in[2];
    const float* b_ih = (const float*)d_in[3];
    const float* b_hh = (const float*)d_in[4];
    const float* W_fc = (const float*)d_in[5];
    const float* b_fc = (const float*)d_in[6];
    float* out = (float*)d_out;

    const int B = in_sizes[0] / (TSEQ * IDIM);   // 8192
    lstm_fused<<<B / BPB, 256, 0, stream>>>(x, W_ih, W_hh, b_ih, b_hh, W_fc, b_fc, out);
}